// Round 11
// baseline (301.401 us; speedup 1.0000x reference)
//
#include <hip/hip_runtime.h>

typedef float f2 __attribute__((ext_vector_type(2)));
typedef float f4 __attribute__((ext_vector_type(4)));

#define PAD 5
#define WSZ 11

// Precomputed normalized 11-tap Gaussian (sigma=1.5) — matches fp32 ref far
// within the 1.4e-2 threshold. Hard-coded to keep weights out of VGPRs.
__device__ __forceinline__ float gw(int k) {
    const float G[WSZ] = {
        0.0010283782f, 0.0075987580f, 0.0360007600f, 0.1093607000f,
        0.2130055600f, 0.2660117400f,
        0.2130055600f, 0.1093607000f, 0.0360007600f, 0.0075987580f, 0.0010283782f };
    return G[k];
}

// Pyramid producer unit (R5-proven body): one 64-lane wave-unit handles one
// (col-half cb, 8-row group rb, channel z): 16 coalesced f4 loads up-front,
// writes p1 (2x2), p2 (4x4), p3 (8x8 via one __shfl_xor pair-reduce).
__device__ __forceinline__ void pyramid_unit(
    const float* __restrict__ img1, const float* __restrict__ img2,
    f2* __restrict__ p1, f2* __restrict__ p2, f2* __restrict__ p3,
    int cb, int rb, int z, int lane)
{
    const size_t ibase = (size_t)z * 262144 + (size_t)(rb * 8) * 512 + cb * 256 + lane * 4;
    const float* b1 = img1 + ibase;
    const float* b2 = img2 + ibase;

    f4 A[8], B[8];
#pragma unroll
    for (int r = 0; r < 8; ++r) {        // 16 independent loads in flight
        A[r] = *(const f4*)(b1 + r * 512);
        B[r] = *(const f4*)(b2 + r * 512);
    }

    f2 u0, u1;
#pragma unroll
    for (int q = 0; q < 2; ++q) {        // q = p2 row within group
        f2 acc = {0.f, 0.f};
#pragma unroll
        for (int h = 0; h < 2; ++h) {    // p1 row within p2 row
            const int rp = q * 2 + h;
            f4 a0 = A[2 * rp], a1 = A[2 * rp + 1];
            f4 c0 = B[2 * rp], c1 = B[2 * rp + 1];
            f2 v0 = { (a0.x + a0.y + a1.x + a1.y) * 0.25f,
                      (c0.x + c0.y + c1.x + c1.y) * 0.25f };
            f2 v1 = { (a0.z + a0.w + a1.z + a1.w) * 0.25f,
                      (c0.z + c0.w + c1.z + c1.w) * 0.25f };
            *(f4*)(p1 + (size_t)z * 65536 + (size_t)(rb * 4 + rp) * 256
                       + cb * 128 + lane * 2) = (f4){ v0.x, v0.y, v1.x, v1.y };
            acc += v0 + v1;
        }
        f2 u = acc * 0.25f;              // p2 pixel (4x4 avg)
        p2[(size_t)z * 16384 + (size_t)(rb * 2 + q) * 128 + cb * 64 + lane] = u;
        if (q == 0) u0 = u; else u1 = u;
    }
    f2 t = u0 + u1;                       // lane's 2 p2 pixels
    t.x += __shfl_xor(t.x, 1);            // + neighbor lane's column
    t.y += __shfl_xor(t.y, 1);
    if ((lane & 1) == 0)
        p3[(size_t)z * 4096 + (size_t)rb * 64 + cb * 32 + (lane >> 1)] = t * 0.25f;
}

// Per-wave SSIM strip body, 2-ROW-PER-ITERATION (R9-proven, byte-identical).
// 64-col x RT-row strip. Two independent H-filter chains per iteration (2x
// intra-wave ILP); fences/bookkeeping halve per row; pair-depth-2 prefetch
// keeps 4 rows in flight. Horizontal 11-tap via two 80-wide private LDS rows
// (same-wave DS ordering; wavefront fences pin the compiler, emit no waitcnt
// -> prefetch loads stay in flight). Vertical 11-tap via a 12-deep register
// ring (static indices after unroll-by-6).
// [Lessons: R2/R6/R10 occupancy levers lose; R7 VALU->LDS trade loses; R8
//  64-VGPR cap spills this body; R4 pooling-at-consume loses.]
template<int RT, bool PLANAR>
__device__ __forceinline__ float ssim_body(
    const float* __restrict__ img1, const float* __restrict__ img2,
    const f2* __restrict__ pair,
    int H, int W, int bx, int sy, int z, f2* st, int lane)
{
    const int ox = bx * 64;
    const int r0 = sy * RT;
    const size_t base = (size_t)z * H * W;

    constexpr int NIT  = RT + 10;        // staged rows (even: RT even)
    constexpr int NIT2 = NIT / 2;        // row pairs
    const float C1 = 1e-4f, C2 = 9e-4f;

    // Per-lane column geometry (iteration-invariant).
    const int c0 = ox - PAD + lane;
    const bool m0 = (c0 >= 0) & (c0 < W);
    const int c0c = min(max(c0, 0), W - 1);
    const int c1 = ox + 59 + lane;                 // halo cols, lanes 0..9
    const bool m1 = (lane < 10) & (c1 < W);
    const int c1c = min(c1, W - 1);

    // Two prefetch slots, each holding a ROW PAIR (a=main col, b=halo col).
    f2 P0a0={0.f,0.f}, P0a1={0.f,0.f}, P0b0={0.f,0.f}, P0b1={0.f,0.f};
    f2 P1a0={0.f,0.f}, P1a1={0.f,0.f}, P1b0={0.f,0.f}, P1b1={0.f,0.f};

    auto issue2 = [&](int y, f2& A0, f2& A1, f2& B0, f2& B1) {
        const int ya = min(max(y, 0), H - 1);          // clamp; mask at consume
        const int yb = min(max(y + 1, 0), H - 1);
        const size_t ra = base + (size_t)ya * W;       // wave-uniform -> SALU
        const size_t rb = base + (size_t)yb * W;
        if (PLANAR) {
            A0 = (f2){ img1[ra + c0c], img2[ra + c0c] };
            A1 = (f2){ img1[rb + c0c], img2[rb + c0c] };
            if (lane < 10) {
                B0 = (f2){ img1[ra + c1c], img2[ra + c1c] };
                B1 = (f2){ img1[rb + c1c], img2[rb + c1c] };
            }
        } else {
            A0 = pair[ra + c0c];
            A1 = pair[rb + c0c];
            if (lane < 10) { B0 = pair[ra + c1c]; B1 = pair[rb + c1c]; }
        }
    };

    issue2(r0 - PAD + 0, P0a0, P0a1, P0b0, P0b1);   // pair 0
    issue2(r0 - PAD + 2, P1a0, P1a1, P1b0, P1b1);   // pair 1

    f2 rmu[12], rsq[12];
    float rxx[12];
    float local = 0.f;
    const f2 zero = {0.f, 0.f};
    f2* st0 = st;          // staging row for even staged-row index
    f2* st1 = st + 80;     // staging row for odd staged-row index

#pragma clang loop unroll(disable)
    for (int q0 = 0; q0 < NIT2; q0 += 6) {
#pragma unroll
        for (int j2 = 0; j2 < 6; ++j2) {
            const int i2 = q0 + j2;
            if (i2 < NIT2) {
                const int it0 = 2 * i2;                // absolute staged-row idx
                const int y0 = r0 - PAD + it0;
                const bool yok0 = (y0 >= 0) & (y0 < H);      // wave-uniform
                const bool yok1 = (y0 + 1 >= 0) & (y0 + 1 < H);

                f2& a0 = (j2 & 1) ? P1a0 : P0a0;       // static slot select
                f2& a1 = (j2 & 1) ? P1a1 : P0a1;
                f2& b0 = (j2 & 1) ? P1b0 : P0b0;
                f2& b1 = (j2 & 1) ? P1b1 : P0b1;
                f2 wa0 = (yok0 & m0) ? a0 : zero;      // vmcnt wait lands here
                f2 wa1 = (yok1 & m0) ? a1 : zero;
                f2 wb0 = (yok0 & m1) ? b0 : zero;
                f2 wb1 = (yok1 & m1) ? b1 : zero;
                issue2(y0 + 4, a0, a1, b0, b1);        // refill: 2 pairs in flight

                __builtin_amdgcn_fence(__ATOMIC_ACQ_REL, "wavefront");
                __builtin_amdgcn_wave_barrier();
                st0[lane] = wa0;
                st1[lane] = wa1;
                if (lane < 10) { st0[64 + lane] = wb0; st1[64 + lane] = wb1; }
                __builtin_amdgcn_fence(__ATOMIC_ACQ_REL, "wavefront");
                __builtin_amdgcn_wave_barrier();

                // Horizontal 11-tap for BOTH rows, interleaved (independent
                // chains -> 2x ILP). Same-wave DS ordering guarantees RAW.
                f2 hmu0 = zero, hsq0 = zero, hmu1 = zero, hsq1 = zero;
                float hxx0 = 0.f, hxx1 = 0.f;
#pragma unroll
                for (int k = 0; k < WSZ; ++k) {
                    const float g = gw(k);
                    f2 p0 = st0[lane + k];
                    f2 p1 = st1[lane + k];
                    hmu0 += p0 * g;  hsq0 += (p0 * p0) * g;  hxx0 += (p0.x * p0.y) * g;
                    hmu1 += p1 * g;  hsq1 += (p1 * p1) * g;  hxx1 += (p1.x * p1.y) * g;
                }
                const int sE = 2 * j2;                 // staged row it0 slot
                const int sO = 2 * j2 + 1;             // staged row it0+1 slot
                rmu[sE] = hmu0; rsq[sE] = hsq0; rxx[sE] = hxx0;
                rmu[sO] = hmu1; rsq[sO] = hsq1; rxx[sO] = hxx1;

                // Vertical 11-tap + SSIM for the two completed output rows
                // (o0 = it0-10 needs slots (2*j2+2+k)%12; o1 = it0-9 needs
                // (2*j2+3+k)%12 — both static after unroll).
                if (it0 >= 10) {
                    f2 vmu0 = zero, vsq0 = zero, vmu1 = zero, vsq1 = zero;
                    float vxx0 = 0.f, vxx1 = 0.f;
#pragma unroll
                    for (int k = 0; k < WSZ; ++k) {
                        const float g = gw(k);
                        const int sA = (2 * j2 + 2 + k) % 12;
                        const int sB = (2 * j2 + 3 + k) % 12;
                        vmu0 += rmu[sA] * g; vsq0 += rsq[sA] * g; vxx0 += rxx[sA] * g;
                        vmu1 += rmu[sB] * g; vsq1 += rsq[sB] * g; vxx1 += rxx[sB] * g;
                    }
                    {
                        const float mu1 = vmu0.x, mu2 = vmu0.y;
                        const float mu11 = mu1 * mu1, mu22 = mu2 * mu2, mu12 = mu1 * mu2;
                        const float sig1 = vsq0.x - mu11;
                        const float sig2 = vsq0.y - mu22;
                        const float sig12 = vxx0 - mu12;
                        const float num = (2.f * mu12 + C1) * (2.f * sig12 + C2);
                        const float den = (mu11 + mu22 + C1) * (sig1 + sig2 + C2);
                        local += num * __builtin_amdgcn_rcpf(den);
                    }
                    {
                        const float mu1 = vmu1.x, mu2 = vmu1.y;
                        const float mu11 = mu1 * mu1, mu22 = mu2 * mu2, mu12 = mu1 * mu2;
                        const float sig1 = vsq1.x - mu11;
                        const float sig2 = vsq1.y - mu22;
                        const float sig12 = vxx1 - mu12;
                        const float num = (2.f * mu12 + C1) * (2.f * sig12 + C2);
                        const float den = (mu11 + mu22 + C1) * (sig1 + sig2 + C2);
                        local += num * __builtin_amdgcn_rcpf(den);
                    }
                }
            }
        }
    }

#pragma unroll
    for (int off = 32; off > 0; off >>= 1) local += __shfl_down(local, off);
    return local;
}

// ONE dispatch, three roles ordered so the CP starts producers first:
//   [pyramid producers: NC*8 blocks]  — 4 units/wave, then fence+count
//   [scale 0:           NC*16 blocks] — no sync at all (hot path untouched)
//   [s1/s2/s3 consumers: NC*13 blocks]— spin-gate on the producer counter
// Producers finish in ~25us of HBM-bound work that overlaps s0's compute
// (HBM only 15% utilized); consumers start then and still finish inside
// s0's ~118us shadow -> the serialized 22us pyramid dispatch disappears.
// Deadlock-free: producers have the lowest blockIdx (dispatched first, no
// deps). Replay-safe: counter zeroed via hipMemsetAsync before each launch.
// Cross-XCD coherence: producer threadfence + release-add; consumer
// acquire-load + acquire fence. s0 blocks (2/3 of all work) carry ZERO sync
// (R6 lesson: per-block fences on the hot path cost ~80us).
__global__ __launch_bounds__(256, 2) void ssim_fused_kernel(
    const float* __restrict__ img1, const float* __restrict__ img2,
    f2* __restrict__ p1, f2* __restrict__ p2, f2* __restrict__ p3,
    unsigned* __restrict__ done, int npb, int ns0,
    double* __restrict__ partials)
{
    __shared__ f2 st_all[4][160];          // per wave: 2 staging rows x 80
    const int lane = threadIdx.x & 63;
    const int wv   = threadIdx.x >> 6;     // 0..3

    const int i = blockIdx.x;

    if (i < npb) {                         // -------- producer role --------
#pragma unroll
        for (int ii = 0; ii < 4; ++ii) {   // 4 pyramid units per wave
            const int u = (i * 4 + wv) * 4 + ii;
            pyramid_unit(img1, img2, p1, p2, p3,
                         u & 1, (u >> 1) & 63, u >> 7, lane);
        }
        __threadfence();                   // agent-scope release of stores
        __syncthreads();
        if (threadIdx.x == 0)
            __hip_atomic_fetch_add(done, 1u, __ATOMIC_RELEASE,
                                   __HIP_MEMORY_SCOPE_AGENT);
        return;
    }

    const int j = i - npb;
    f2* st = st_all[wv];
    float local;

    if (j < ns0) {                         // -------- scale 0 (no sync) ----
        const int z = j >> 4, r = j & 15;
        local = ssim_body<64, true>(img1, img2, nullptr, 512, 512,
                                    r & 7, (r >> 3) * 4 + wv, z, st, lane);
    } else {                               // -------- consumers ------------
        if (threadIdx.x == 0) {
            while (__hip_atomic_load(done, __ATOMIC_ACQUIRE,
                                     __HIP_MEMORY_SCOPE_AGENT) < (unsigned)npb)
                __builtin_amdgcn_s_sleep(64);
        }
        __syncthreads();
        __builtin_amdgcn_fence(__ATOMIC_ACQUIRE, "agent");

        const int c = j - ns0;
        const int z = c / 13;              // magic-mul div
        const int r = c - z * 13;
        if (r < 8) {                       // scale 1: RT=32, 256x256
            local = ssim_body<32, false>(nullptr, nullptr, p1, 256, 256,
                                         r & 3, (r >> 2) * 4 + wv, z, st, lane);
        } else if (r < 12) {               // scale 2: RT=16, 128x128
            const int l = r - 8;
            local = ssim_body<16, false>(nullptr, nullptr, p2, 128, 128,
                                         l & 1, (l >> 1) * 4 + wv, z, st, lane);
        } else {                           // scale 3: RT=16, 64x64
            local = ssim_body<16, false>(nullptr, nullptr, p3, 64, 64,
                                         0, wv, z, st, lane);
        }
    }
    if (lane == 0) partials[(size_t)j * 4 + wv] = (double)local;
}

// Single-block reduce of all per-wave partials; decodes wave->scale from the
// [s0 NC*16][cons NC*13] block layout. ~45 KB of L2-hot doubles, few us.
__global__ __launch_bounds__(256) void finalize_kernel(
    const double* __restrict__ partials, float* __restrict__ out,
    int nw, int ns0,
    double c0, double c1, double c2, double c3)
{
    double s[4] = {0.0, 0.0, 0.0, 0.0};
    for (int idx = threadIdx.x; idx < nw; idx += 256) {
        const int b = idx >> 2;            // block index (4 waves/block)
        int sc;
        if (b < ns0) sc = 0;
        else {
            const int c = b - ns0;
            const int z = c / 13;
            const int r = c - z * 13;
            sc = (r < 8) ? 1 : (r < 12) ? 2 : 3;
        }
        s[sc] += partials[idx];
    }
    __shared__ double sm[4][256];
    sm[0][threadIdx.x] = s[0]; sm[1][threadIdx.x] = s[1];
    sm[2][threadIdx.x] = s[2]; sm[3][threadIdx.x] = s[3];
    __syncthreads();
    if (threadIdx.x == 0) {
        const double w[4] = {0.0448, 0.2856, 0.3001, 0.2363};
        const double cnt[4] = {c0, c1, c2, c3};
        double loss = 0.0;
#pragma unroll
        for (int sc = 0; sc < 4; ++sc) {
            double t = 0.0;
            for (int k = 0; k < 256; ++k) t += sm[sc][k];
            loss += w[sc] * (1.0 - t / cnt[sc]);
        }
        out[0] = (float)loss;
    }
}

extern "C" void kernel_launch(void* const* d_in, const int* in_sizes, int n_in,
                              void* d_out, int out_size, void* d_ws, size_t ws_size,
                              hipStream_t stream) {
    const float* img1 = (const float*)d_in[0];
    const float* img2 = (const float*)d_in[1];
    float* out = (float*)d_out;

    const int H0 = 512, W0 = 512;
    const int NC = in_sizes[0] / (H0 * W0);  // 48

    unsigned* done = (unsigned*)d_ws;                 // producer counter
    double* partials = (double*)((char*)d_ws + 64);   // NC*29*4 doubles (<45KB)
    f2* p1 = (f2*)((char*)d_ws + 65536);              // NC*256*256
    f2* p2 = p1 + (size_t)NC * 256 * 256;             // NC*128*128
    f2* p3 = p2 + (size_t)NC * 128 * 128;             // NC*64*64

    // Zero the producer counter (graph-capturable stream op; replay-safe).
    hipMemsetAsync(done, 0, sizeof(unsigned), stream);

    const int NPB = NC * 8;               // producer blocks (4 waves x 4 units)
    const int NS0 = NC * 16;              // scale-0 blocks
    const int NBLK = NPB + NS0 + NC * 13; // + consumer blocks
    ssim_fused_kernel<<<dim3(NBLK), 256, 0, stream>>>(
        img1, img2, p1, p2, p3, done, NPB, NS0, partials);

    const double c0 = (double)NC * 512.0 * 512.0;
    const double c1 = (double)NC * 256.0 * 256.0;
    const double c2 = (double)NC * 128.0 * 128.0;
    const double c3 = (double)NC * 64.0 * 64.0;
    finalize_kernel<<<1, 256, 0, stream>>>(partials, out, (NS0 + NC * 13) * 4,
                                           NS0, c0, c1, c2, c3);
}